// Round 19
// baseline (656.628 us; speedup 1.0000x reference)
//
#include <hip/hip_runtime.h>
#include <hip/hip_bf16.h>
#include <math.h>

#define HD 128
#define MPB 8
#define EPB 2

typedef __attribute__((ext_vector_type(8))) short short8;
typedef __attribute__((ext_vector_type(4))) float f32x4;
typedef unsigned short ushort_t;
typedef unsigned int uint32;

#define MFMA(a, b, c) __builtin_amdgcn_mfma_f32_16x16x32_bf16(a, b, c, 0, 0, 0)

// ---- ws layout ----
#define WS_TE   0        // 16*128
#define WS_TM   2048     // 4*128
#define WS_AW2  2560     // 9*128
#define WS_EW2  3712     // 3*128
#define WS_CVEC 4096     // 128
#define FB_OFF 32768

// fb byte offsets (each 128x128 bf16 weight = 32768 B, kt-major 1KB tiles)
#define FB_W1(l)  ((size_t)(l) * 65536)
#define FB_W2(l)  ((size_t)(l) * 65536 + 32768)
#define FB_WA     ((size_t)131072)
#define FB_WB     ((size_t)163840)
#define FB_WC     ((size_t)196608)
#define FB_WM     ((size_t)229376)
#define FB_ATOM   ((size_t)262144)
#define FB_EDGE   ((size_t)270336)

__device__ __forceinline__ float bf2f(ushort_t u) {
  union { float f; uint32 i; } c; c.i = ((uint32)u) << 16; return c.f;
}
__device__ __forceinline__ ushort_t f2bf(float f) {
  union { float ff; uint32 u; } c; c.ff = f;
  uint32 r = c.u + 0x7fff + ((c.u >> 16) & 1);
  return (ushort_t)(r >> 16);
}
__device__ __forceinline__ int off256(int row, int by) {
  return row * 256 + (by ^ ((row & 7) << 4));
}
// staging tails: bytes [192,256) of each 256B row, K=32 bf16
__device__ __forceinline__ int offS(int row, int by) {
  return row * 256 + 192 + (by ^ ((row & 3) << 4));
}
__device__ __forceinline__ void store8(char* p, const float* v) {
  short8 r;
  #pragma unroll
  for (int j = 0; j < 8; ++j) r[j] = (short)f2bf(v[j]);
  *(short8*)p = r;
}

// ================= precompute: f32 tables =================
__global__ __launch_bounds__(128) void precompute_kernel(
    const float* __restrict__ type_emb, const float* __restrict__ atom_W,
    const float* __restrict__ atom_b, const float* __restrict__ edge_W,
    const float* __restrict__ edge_b, const float* __restrict__ motif_W,
    const float* __restrict__ me_W, const float* __restrict__ me_b,
    float n_nodes, float* __restrict__ ws)
{
  const int t = threadIdx.x;
  const int r = blockIdx.x;
  float acc = 0.0f;
  if (r < 16) {
    const int sc = r >> 2, ec = r & 3;
    for (int c = 0; c < HD; ++c)
      acc += (type_emb[sc*HD + c] + type_emb[ec*HD + c]) * me_W[c*HD + t];
    ws[WS_TE + r*HD + t] = acc;
  } else if (r < 20) {
    const int ty = r - 16;
    for (int c = 0; c < HD; ++c) {
      float tv = type_emb[ty*HD + c] * (c >= 64 ? n_nodes : 1.0f);
      acc += tv * motif_W[(HD + c)*HD + t];
    }
    ws[WS_TM + ty*HD + t] = acc;
  } else if (r < 29) {
    const int a = r - 20;
    for (int c = 0; c < HD; ++c)
      acc += atom_W[a*HD + c] * me_W[(HD + c)*HD + t];
    ws[WS_AW2 + a*HD + t] = acc;
  } else if (r < 32) {
    const int a = r - 29;
    for (int c = 0; c < HD; ++c)
      acc += edge_W[a*HD + c] * me_W[(HD + c)*HD + t];
    ws[WS_EW2 + a*HD + t] = acc;
  } else {
    acc = me_b[t];
    for (int c = 0; c < HD; ++c)
      acc += (6.0f*atom_b[c] + 8.0f*edge_b[c]) * me_W[(HD + c)*HD + t];
    ws[WS_CVEC + t] = acc;
  }
}

// ================= precompute: bf16 MFMA fragment buffer =================
__global__ __launch_bounds__(64) void frag_kernel(
    const float* __restrict__ conv_W1, const float* __restrict__ conv_W2,
    const float* __restrict__ emlp_W, const float* __restrict__ motif_W,
    const float* __restrict__ atom_W, const float* __restrict__ edge_W,
    ushort_t* __restrict__ fbo)
{
  const int bid = blockIdx.x, l = threadIdx.x;
  int wi, kt, nt;
  if (bid < 256) { wi = bid >> 5; kt = (bid >> 3) & 3; nt = bid & 7; }
  else { int r = bid - 256; wi = 8 + (r >> 3); kt = 0; nt = r & 7; }
  const float* src; int Klim = 128;
  switch (wi) {
    case 0: src = conv_W1; break;
    case 1: src = conv_W2; break;
    case 2: src = conv_W1 + 16384; break;
    case 3: src = conv_W2 + 16384; break;
    case 4: src = emlp_W; break;
    case 5: src = emlp_W + 16384; break;
    case 6: src = emlp_W + 32768; break;
    case 7: src = motif_W; break;
    case 8: src = atom_W; Klim = 9; break;
    default: src = edge_W; Klim = 3; break;
  }
  size_t base = (wi < 8) ? (size_t)wi * 16384 : (size_t)131072 + (size_t)(wi - 8) * 4096;
  ushort_t* dst = fbo + base + ((size_t)(kt * 8 + nt) * 64 + l) * 8;
  #pragma unroll
  for (int j = 0; j < 8; ++j) {
    int k = kt * 32 + ((l >> 4) << 3) + j;
    int n = nt * 16 + (l & 15);
    float f = (k < Klim) ? src[k * HD + n] : 0.0f;
    dst[j] = f2bf(f);
  }
}

// ================= motif kernel =================
// r17 structure (column-split GEMMs, B from L2, ping-pong Hb<->Tb) with LDS
// cut to ~54,272 B (<= 54,613 = 3 blocks/CU): Rx dropped by reordering emlp
// to compute ea@WC FIRST, barrier (ea dead), then h@WA + h@WB, R -> EAb all
// 80 rows; compact dst-sorted zl/zoff. launch_bounds STAYS (256,2): the 2nd
// arg only CAPS registers (caps below natural ~200 total spilled in
// r3/4/10/13/16); occupancy rises to 3 blocks/CU via LDS fit alone.
__global__ __launch_bounds__(256, 2) void motif_kernel(
    const float* __restrict__ x, const float* __restrict__ eag,
    const int* __restrict__ motif_nodes, const int* __restrict__ motif_types,
    const int* __restrict__ m_src, const int* __restrict__ m_dst,
    const int* __restrict__ m_eidx,
    const float* __restrict__ atom_b, const float* __restrict__ edge_b,
    const float* __restrict__ conv_b1, const float* __restrict__ conv_b2,
    const float* __restrict__ conv_eps,
    const float* __restrict__ attn_W, const float* __restrict__ attn_b,
    const float* __restrict__ emlp_b, const float* __restrict__ motif_b,
    const float* __restrict__ wsf, const ushort_t* __restrict__ fb,
    float* __restrict__ out)
{
  __shared__ __align__(16) char Hb[64 * 256];    // xp tails -> h0 -> (ping-pong) -> h final
  __shared__ __align__(16) char Tb[64 * 256];    // z / r ping-pong
  __shared__ __align__(16) char EAb[80 * 256];   // ep tails -> ea -> R(80 rows) -> cat(rows 0-15)
  __shared__ unsigned char zl[8][10];            // dst-sorted edge list (e | s<<4)
  __shared__ unsigned char zoff[8][8];           // start offset per dst k
  __shared__ unsigned char gsr[80], gdr[80];
  __shared__ float qa[64];

  const int tid  = threadIdx.x;
  const int lane = tid & 63;
  const int wid  = tid >> 6;
  const int cl   = lane & 15;
  const int rg   = lane >> 4;
  const int rg16 = rg << 4;
  const int m0   = blockIdx.x * MPB;
  const int rb   = wid * 16;
  const int arow = rb + cl;
  const char* fbb = (const char*)fb;

  // B-fragment straight from L2: tile T of weight at byte offset OFF
#define BFR(OFF, T) (*(const short8*)(fbb + (OFF) + (((size_t)(T) * 64 + lane) * 16)))

  // ---------- init: tails + tables ----------
  if (tid < 64) qa[tid] = 0.0f;
  if (tid < 80) {
    int m = tid / 10;
    gsr[tid] = (unsigned char)(m * 8 + m_src[(size_t)m0 * 10 + tid]);
    gdr[tid] = (unsigned char)(m * 8 + m_dst[(size_t)m0 * 10 + tid]);
  }
  if (tid >= 192 && tid < 200) {   // dst-sorted compact z-list
    int m = tid - 192;
    int cnt = 0;
    for (int k = 0; k < 8; ++k) {
      zoff[m][k] = (unsigned char)cnt;
      for (int e = 0; e < 10; ++e) {
        int s = m_src[(size_t)(m0 + m) * 10 + e];
        int d = m_dst[(size_t)(m0 + m) * 10 + e];
        if (d == k) zl[m][cnt++] = (unsigned char)(e | (s << 4));
      }
    }
  }
  for (int i = tid; i < 64 * 32; i += 256) {
    int row = i >> 5, k = i & 31;
    int nd = motif_nodes[(size_t)m0 * 8 + row];
    float f = (k < 9) ? x[(size_t)nd * 9 + k] : 0.0f;
    *(ushort_t*)(Hb + offS(row, 2 * k)) = f2bf(f);
  }
  for (int i = tid; i < 80 * 32; i += 256) {
    int row = i >> 5, k = i & 31;
    int ei = m_eidx[(size_t)m0 * 10 + row];
    float f = (k < 3) ? eag[(size_t)ei * 3 + k] : 0.0f;
    *(ushort_t*)(EAb + offS(row, 2 * k)) = f2bf(f);
  }
  __syncthreads();   // B1

  // ---------- embed (row-split, K=32, B from L2): h0 -> Hb, ea -> EAb ----------
  {
    {
      short8 a = *(const short8*)(Hb + offS(arow, rg16));
      f32x4 acc[8];
      #pragma unroll
      for (int nt = 0; nt < 8; ++nt) { float bv = atom_b[nt * 16 + cl]; acc[nt] = f32x4{bv, bv, bv, bv}; }
      #pragma unroll
      for (int nt = 0; nt < 8; ++nt) acc[nt] = MFMA(a, BFR(FB_ATOM, nt), acc[nt]);
      #pragma unroll
      for (int nt = 0; nt < 8; ++nt)
        #pragma unroll
        for (int i = 0; i < 4; ++i)
          *(ushort_t*)(Hb + off256(rb + rg * 4 + i, (nt * 16 + cl) * 2)) = f2bf(acc[nt][i]);
    }
    for (int mt = wid; mt < 5; mt += 4) {
      int rbe = mt * 16, row = rbe + cl;
      short8 a = *(const short8*)(EAb + offS(row, rg16));
      f32x4 acc[8];
      #pragma unroll
      for (int nt = 0; nt < 8; ++nt) { float bv = edge_b[nt * 16 + cl]; acc[nt] = f32x4{bv, bv, bv, bv}; }
      #pragma unroll
      for (int nt = 0; nt < 8; ++nt) acc[nt] = MFMA(a, BFR(FB_EDGE, nt), acc[nt]);
      #pragma unroll
      for (int nt = 0; nt < 8; ++nt)
        #pragma unroll
        for (int i = 0; i < 4; ++i)
          *(ushort_t*)(EAb + off256(rbe + rg * 4 + i, (nt * 16 + cl) * 2)) = f2bf(acc[nt][i]);
    }
  }
  __syncthreads();   // B2

  // ---------- conv layers (ping-pong bufA <-> bufB, 3 barriers/layer) ----------
  #pragma unroll 1
  for (int l = 0; l < 2; ++l) {
    const float epl = 1.0f + conv_eps[l];
    char* bufA = (l == 0) ? Hb : Tb;   // h at layer start
    char* bufB = (l == 0) ? Tb : Hb;

    // z: read bufA (+EAb), write bufB. one barrier.
    {
      float zf[4][8];
      #pragma unroll
      for (int it = 0; it < 4; ++it) {
        const int idx = tid + it * 256;
        const int row = idx >> 4;
        const int by  = (idx & 15) << 4;
        const int m = row >> 3, k = row & 7;
        short8 hv = *(const short8*)(bufA + off256(row, by));
        #pragma unroll
        for (int j = 0; j < 8; ++j) zf[it][j] = epl * bf2f((ushort_t)hv[j]);
        const int ib = zoff[m][k];
        const int ie = (k < 7) ? (int)zoff[m][k + 1] : 10;
        for (int j2 = ib; j2 < ie; ++j2) {
          const int pp = zl[m][j2];
          short8 ev = *(const short8*)(EAb  + off256(m * 10 + (pp & 15), by));
          short8 sv = *(const short8*)(bufA + off256(m * 8  + (pp >> 4), by));
          #pragma unroll
          for (int j = 0; j < 8; ++j)
            zf[it][j] += bf2f((ushort_t)ev[j]) * bf2f((ushort_t)sv[j]);
        }
        store8(bufB + off256(row, by), zf[it]);
      }
    }
    __syncthreads();   // z ready in bufB

    // GEMM1 (column-split): r = relu(z @ W1 + b1), bufB -> bufA
    {
      f32x4 acc[4][2];
      #pragma unroll
      for (int mt = 0; mt < 4; ++mt)
        #pragma unroll
        for (int j = 0; j < 2; ++j) {
          float bv = conv_b1[l * HD + (2 * wid + j) * 16 + cl];
          acc[mt][j] = f32x4{bv, bv, bv, bv};
        }
      #pragma unroll
      for (int kt = 0; kt < 4; ++kt) {
        short8 b0 = BFR(FB_W1(l), kt * 8 + 2 * wid);
        short8 b1 = BFR(FB_W1(l), kt * 8 + 2 * wid + 1);
        #pragma unroll
        for (int mt = 0; mt < 4; ++mt) {
          short8 a = *(const short8*)(bufB + off256(mt * 16 + cl, kt * 64 + rg16));
          acc[mt][0] = MFMA(a, b0, acc[mt][0]);
          acc[mt][1] = MFMA(a, b1, acc[mt][1]);
        }
      }
      #pragma unroll
      for (int mt = 0; mt < 4; ++mt)
        #pragma unroll
        for (int j = 0; j < 2; ++j)
          #pragma unroll
          for (int i = 0; i < 4; ++i)
            *(ushort_t*)(bufA + off256(mt * 16 + rg * 4 + i, ((2 * wid + j) * 16 + cl) * 2))
                = f2bf(fmaxf(acc[mt][j][i], 0.0f));
    }
    __syncthreads();   // r ready in bufA

    // GEMM2 (column-split): h = r @ W2 + b2, bufA -> bufB
    {
      f32x4 acc[4][2];
      #pragma unroll
      for (int mt = 0; mt < 4; ++mt)
        #pragma unroll
        for (int j = 0; j < 2; ++j) {
          float bv = conv_b2[l * HD + (2 * wid + j) * 16 + cl];
          acc[mt][j] = f32x4{bv, bv, bv, bv};
        }
      #pragma unroll
      for (int kt = 0; kt < 4; ++kt) {
        short8 b0 = BFR(FB_W2(l), kt * 8 + 2 * wid);
        short8 b1 = BFR(FB_W2(l), kt * 8 + 2 * wid + 1);
        #pragma unroll
        for (int mt = 0; mt < 4; ++mt) {
          short8 a = *(const short8*)(bufA + off256(mt * 16 + cl, kt * 64 + rg16));
          acc[mt][0] = MFMA(a, b0, acc[mt][0]);
          acc[mt][1] = MFMA(a, b1, acc[mt][1]);
        }
      }
      #pragma unroll
      for (int mt = 0; mt < 4; ++mt)
        #pragma unroll
        for (int j = 0; j < 2; ++j)
          #pragma unroll
          for (int i = 0; i < 4; ++i)
            *(ushort_t*)(bufB + off256(mt * 16 + rg * 4 + i, ((2 * wid + j) * 16 + cl) * 2))
                = f2bf(acc[mt][j][i]);
    }
    __syncthreads();   // h ready in bufB  (l=0 -> Tb, l=1 -> Hb)
  }

  // ---------- attention (h final in Hb) ----------
  {
    int j = tid & 3;
    for (int r = tid >> 2; r < 80; r += 64) {
      float p = 0.0f;
      #pragma unroll
      for (int g = 0; g < 4; ++g) {
        short8 ev = *(const short8*)(EAb + off256(r, (j * 4 + g) << 4));
        const int c0 = j * 32 + g * 8;
        #pragma unroll
        for (int jj = 0; jj < 8; ++jj)
          p += bf2f((ushort_t)ev[jj]) * attn_W[HD + c0 + jj];
      }
      p += __shfl_xor(p, 1); p += __shfl_xor(p, 2);
      if (j == 0) {
        atomicAdd(&qa[gsr[r]], p);
        atomicAdd(&qa[gdr[r]], p);
      }
    }
  }
  __syncthreads();
  {
    int j = tid & 3, r = tid >> 2;
    float p = 0.0f;
    #pragma unroll
    for (int g = 0; g < 4; ++g) {
      short8 hv = *(const short8*)(Hb + off256(r, (j * 4 + g) << 4));
      const int c0 = j * 32 + g * 8;
      #pragma unroll
      for (int jj = 0; jj < 8; ++jj)
        p += bf2f((ushort_t)hv[jj]) * attn_W[c0 + jj];
    }
    p += __shfl_xor(p, 1); p += __shfl_xor(p, 2);
    if (j == 0) qa[r] = 1.0f / (1.0f + __expf(-(p + qa[r] + attn_b[0])));
  }
  __syncthreads();

  // ---------- fused emlp, reordered: ea@WC first, then h@WA + h@WB ----------
  // After the mid barrier EAb (ea) is dead -> R's 80 rows land in EAb.
  {
    f32x4 acc[5][2];
    #pragma unroll
    for (int et = 0; et < 5; ++et) { acc[et][0] = f32x4{0, 0, 0, 0}; acc[et][1] = f32x4{0, 0, 0, 0}; }
    // w = 2: ea @ WC  (reads EAb)
    #pragma unroll
    for (int kt = 0; kt < 4; ++kt) {
      short8 b0 = BFR(FB_WC, kt * 8 + 2 * wid);
      short8 b1 = BFR(FB_WC, kt * 8 + 2 * wid + 1);
      #pragma unroll
      for (int et = 0; et < 5; ++et) {
        short8 a = *(const short8*)(EAb + off256(et * 16 + cl, kt * 64 + rg16));
        acc[et][0] = MFMA(a, b0, acc[et][0]);
        acc[et][1] = MFMA(a, b1, acc[et][1]);
      }
    }
    __syncthreads();   // all EAb (ea) reads complete; EAb reusable for R
    // w = 0: h[src] @ WA ; w = 1: h[dst] @ WB  (reads Hb only)
    #pragma unroll 1
    for (int w = 0; w < 2; ++w) {
      const size_t wo = (w == 0) ? FB_WA : FB_WB;
      #pragma unroll
      for (int kt = 0; kt < 4; ++kt) {
        short8 b0 = BFR(wo, kt * 8 + 2 * wid);
        short8 b1 = BFR(wo, kt * 8 + 2 * wid + 1);
        #pragma unroll
        for (int et = 0; et < 5; ++et) {
          const int r_ = et * 16 + cl;
          const int ar = (w == 0) ? (int)gsr[r_] : (int)gdr[r_];
          short8 a = *(const short8*)(Hb + off256(ar, kt * 64 + rg16));
          acc[et][0] = MFMA(a, b0, acc[et][0]);
          acc[et][1] = MFMA(a, b1, acc[et][1]);
        }
      }
    }
    // epilogue: write R -> EAb rows 0-79
    #pragma unroll
    for (int et = 0; et < 5; ++et)
      #pragma unroll
      for (int j = 0; j < 2; ++j)
        #pragma unroll
        for (int i = 0; i < 4; ++i)
          *(ushort_t*)(EAb + off256(et * 16 + rg * 4 + i, ((2 * wid + j) * 16 + cl) * 2))
              = f2bf(acc[et][j][i]);
  }
  __syncthreads();   // R ready

  // ---------- cat = hn + 0.1*sum relu(R+eb); write EAb rows 0-15 ----------
  float cv[8];
  if (tid < 128) {
    const int m  = tid >> 4;
    const int by = (tid & 15) << 4;
    const int c0 = (tid & 15) * 8;
    #pragma unroll
    for (int j = 0; j < 8; ++j) cv[j] = 0.0f;
    #pragma unroll
    for (int e = 0; e < 10; ++e) {
      short8 rv = *(const short8*)(EAb + off256(m * 10 + e, by));
      #pragma unroll
      for (int j = 0; j < 8; ++j)
        cv[j] += fmaxf(bf2f((ushort_t)rv[j]) + emlp_b[c0 + j], 0.0f);
    }
    #pragma unroll
    for (int j = 0; j < 8; ++j) cv[j] *= 0.1f;
    #pragma unroll
    for (int k = 0; k < 8; ++k) {
      short8 hv = *(const short8*)(Hb + off256(m * 8 + k, by));
      const float a = qa[m * 8 + k];
      #pragma unroll
      for (int j = 0; j < 8; ++j) cv[j] += a * bf2f((ushort_t)hv[j]);
    }
  }
  __syncthreads();   // all R reads done before cat overwrites rows 0-15
  if (tid < 128) {
    store8(EAb + off256(tid >> 4, (tid & 15) << 4), cv);
  } else {
    const int i = tid - 128;
    short8 z{};
    *(short8*)(EAb + off256(8 + (i >> 4), (i & 15) << 4)) = z;
  }
  __syncthreads();   // cat tile ready

  // ---------- final: out = cat @ motifW_top + TM[type] + motif_b ----------
  {
    f32x4 acc[2];
    acc[0] = f32x4{0, 0, 0, 0}; acc[1] = f32x4{0, 0, 0, 0};
    #pragma unroll
    for (int kt = 0; kt < 4; ++kt) {
      short8 a = *(const short8*)(EAb + off256(cl, kt * 64 + rg16));
      #pragma unroll
      for (int j = 0; j < 2; ++j)
        acc[j] = MFMA(a, BFR(FB_WM, kt * 8 + 2 * wid + j), acc[j]);
    }
    #pragma unroll
    for (int j = 0; j < 2; ++j)
      #pragma unroll
      for (int i = 0; i < 4; ++i) {
        int row = rg * 4 + i;
        if (row < 8) {
          int col = (wid * 2 + j) * 16 + cl;
          int ty = motif_types[m0 + row];
          out[(size_t)(m0 + row) * HD + col] = acc[j][i] + motif_b[col] + wsf[WS_TM + ty * HD + col];
        }
      }
  }
#undef BFR
}

// ================= edge kernel =================
__global__ __launch_bounds__(256) void edge_kernel(
    const float* __restrict__ x, const float* __restrict__ eag,
    const int* __restrict__ motif_types, const int* __restrict__ mei,
    const int* __restrict__ attr_nodes, const int* __restrict__ attr_edges,
    const float* __restrict__ ws, float* __restrict__ out, int ME_)
{
  __shared__ int   ani[EPB][6];
  __shared__ int   aei[EPB][8];
  __shared__ float sxl[EPB][9];
  __shared__ float sel[EPB][3];
  __shared__ int   tei[EPB];

  const int tid = threadIdx.x;
  const int t = tid & (HD - 1);
  const int g = tid >> 7;
  const int me0 = blockIdx.x * EPB;

  if (tid < EPB*6) ani[tid/6][tid%6] = attr_nodes[(size_t)(me0 + tid/6)*6 + tid%6];
  if (tid >= 32 && tid < 32 + EPB*8) { int i = tid-32; aei[i/8][i%8] = attr_edges[(size_t)(me0 + i/8)*8 + i%8]; }
  if (tid >= 64 && tid < 64 + EPB) {
    const int e = tid - 64;
    const int a0 = mei[me0 + e], b0 = mei[ME_ + me0 + e];
    tei[e] = motif_types[a0]*4 + motif_types[b0];
  }
  __syncthreads();

  if (tid < EPB*9) {
    const int e = tid/9, a = tid%9;
    float s = 0.0f;
    #pragma unroll
    for (int p = 0; p < 6; ++p) s += x[(size_t)ani[e][p]*9 + a];
    sxl[e][a] = s;
  }
  if (tid >= 32 && tid < 32 + EPB*3) {
    const int i = tid-32, e = i/3, a = i%3;
    float s = 0.0f;
    #pragma unroll
    for (int p = 0; p < 8; ++p) s += eag[(size_t)aei[e][p]*3 + a];
    sel[e][a] = s;
  }
  __syncthreads();

  float acc = ws[WS_CVEC + t] + ws[WS_TE + tei[g]*HD + t];
  #pragma unroll
  for (int a = 0; a < 9; ++a) acc += sxl[g][a] * ws[WS_AW2 + a*HD + t];
  #pragma unroll
  for (int a = 0; a < 3; ++a) acc += sel[g][a] * ws[WS_EW2 + a*HD + t];
  out[(size_t)(me0 + g)*HD + t] = acc;
}

extern "C" void kernel_launch(void* const* d_in, const int* in_sizes, int n_in,
                              void* d_out, int out_size, void* d_ws, size_t ws_size,
                              hipStream_t stream) {
  const float* x          = (const float*)d_in[0];
  const float* eag        = (const float*)d_in[1];
  const int*   motif_nodes= (const int*)d_in[2];
  const int*   motif_types= (const int*)d_in[3];
  const int*   m_src      = (const int*)d_in[4];
  const int*   m_dst      = (const int*)d_in[5];
  const int*   m_eidx     = (const int*)d_in[6];
  const int*   mei        = (const int*)d_in[7];
  const int*   attr_nodes = (const int*)d_in[8];
  const int*   attr_edges = (const int*)d_in[9];
  const float* type_emb   = (const float*)d_in[10];
  const float* atom_W     = (const float*)d_in[11];
  const float* atom_b     = (const float*)d_in[12];
  const float* edge_W     = (const float*)d_in[13];
  const float* edge_b     = (const float*)d_in[14];
  const float* conv_W1    = (const float*)d_in[15];
  const float* conv_b1    = (const float*)d_in[16];
  const float* conv_W2    = (const float*)d_in[17];
  const float* conv_b2    = (const float*)d_in[18];
  const float* conv_eps   = (const float*)d_in[19];
  const float* attn_W     = (const float*)d_in[20];
  const float* attn_b     = (const float*)d_in[21];
  const float* emlp_W     = (const float*)d_in[22];
  const float* emlp_b     = (const float*)d_in[23];
  const float* motif_W    = (const float*)d_in[24];
  const float* motif_b    = (const float*)d_in[25];
  const float* me_W       = (const float*)d_in[26];
  const float* me_b       = (const float*)d_in[27];

  const int N_  = in_sizes[0] / 9;
  const int M_  = in_sizes[2] / 8;
  const int ME_ = in_sizes[7] / 2;

  float* wsf = (float*)d_ws;
  ushort_t* fb = (ushort_t*)((char*)d_ws + FB_OFF);
  float* out = (float*)d_out;

  precompute_kernel<<<33, 128, 0, stream>>>(type_emb, atom_W, atom_b, edge_W, edge_b,
                                            motif_W, me_W, me_b, (float)N_, wsf);
  frag_kernel<<<272, 64, 0, stream>>>(conv_W1, conv_W2, emlp_W, motif_W, atom_W, edge_W, fb);
  motif_kernel<<<M_/MPB, 256, 0, stream>>>(x, eag, motif_nodes, motif_types, m_src, m_dst, m_eidx,
      atom_b, edge_b, conv_b1, conv_b2, conv_eps, attn_W, attn_b, emlp_b, motif_b,
      wsf, fb, out);
  edge_kernel<<<ME_/EPB, 256, 0, stream>>>(x, eag, motif_types, mei, attr_nodes, attr_edges,
                                           wsf, out + (size_t)M_*HD, ME_);
}

// Round 20
// 542.069 us; speedup vs baseline: 1.2113x; 1.2113x over previous
//
#include <hip/hip_runtime.h>
#include <hip/hip_bf16.h>
#include <math.h>

#define HD 128
#define MPB 8
#define EPB 2

typedef __attribute__((ext_vector_type(8))) short short8;
typedef __attribute__((ext_vector_type(4))) float f32x4;
typedef unsigned short ushort_t;
typedef unsigned int uint32;

#define MFMA(a, b, c) __builtin_amdgcn_mfma_f32_16x16x32_bf16(a, b, c, 0, 0, 0)

// ---- ws layout ----
#define WS_TE   0        // 16*128
#define WS_TM   2048     // 4*128
#define WS_AW2  2560     // 9*128
#define WS_EW2  3712     // 3*128
#define WS_CVEC 4096     // 128
#define FB_OFF 32768

// fb byte offsets (each 128x128 bf16 weight = 32768 B, kt-major 1KB tiles;
// half0 = tiles 0-15 (kt 0,1), half1 = tiles 16-31 (kt 2,3))
#define FB_W1(l)  ((size_t)(l) * 65536)
#define FB_W2(l)  ((size_t)(l) * 65536 + 32768)
#define FB_WA     ((size_t)131072)
#define FB_WM     ((size_t)229376)
#define FB_ATOM   ((size_t)262144)
#define FB_EDGE   ((size_t)270336)

__device__ __forceinline__ float bf2f(ushort_t u) {
  union { float f; uint32 i; } c; c.i = ((uint32)u) << 16; return c.f;
}
__device__ __forceinline__ ushort_t f2bf(float f) {
  union { float ff; uint32 u; } c; c.ff = f;
  uint32 r = c.u + 0x7fff + ((c.u >> 16) & 1);
  return (ushort_t)(r >> 16);
}
__device__ __forceinline__ int off256(int row, int by) {
  return row * 256 + (by ^ ((row & 7) << 4));
}
// staging tails: bytes [192,256) of each 256B row, K=32 bf16
__device__ __forceinline__ int offS(int row, int by) {
  return row * 256 + 192 + (by ^ ((row & 3) << 4));
}
__device__ __forceinline__ void store8(char* p, const float* v) {
  short8 r;
  #pragma unroll
  for (int j = 0; j < 8; ++j) r[j] = (short)f2bf(v[j]);
  *(short8*)p = r;
}

// ================= precompute: f32 tables =================
__global__ __launch_bounds__(128) void precompute_kernel(
    const float* __restrict__ type_emb, const float* __restrict__ atom_W,
    const float* __restrict__ atom_b, const float* __restrict__ edge_W,
    const float* __restrict__ edge_b, const float* __restrict__ motif_W,
    const float* __restrict__ me_W, const float* __restrict__ me_b,
    float n_nodes, float* __restrict__ ws)
{
  const int t = threadIdx.x;
  const int r = blockIdx.x;
  float acc = 0.0f;
  if (r < 16) {
    const int sc = r >> 2, ec = r & 3;
    for (int c = 0; c < HD; ++c)
      acc += (type_emb[sc*HD + c] + type_emb[ec*HD + c]) * me_W[c*HD + t];
    ws[WS_TE + r*HD + t] = acc;
  } else if (r < 20) {
    const int ty = r - 16;
    for (int c = 0; c < HD; ++c) {
      float tv = type_emb[ty*HD + c] * (c >= 64 ? n_nodes : 1.0f);
      acc += tv * motif_W[(HD + c)*HD + t];
    }
    ws[WS_TM + ty*HD + t] = acc;
  } else if (r < 29) {
    const int a = r - 20;
    for (int c = 0; c < HD; ++c)
      acc += atom_W[a*HD + c] * me_W[(HD + c)*HD + t];
    ws[WS_AW2 + a*HD + t] = acc;
  } else if (r < 32) {
    const int a = r - 29;
    for (int c = 0; c < HD; ++c)
      acc += edge_W[a*HD + c] * me_W[(HD + c)*HD + t];
    ws[WS_EW2 + a*HD + t] = acc;
  } else {
    acc = me_b[t];
    for (int c = 0; c < HD; ++c)
      acc += (6.0f*atom_b[c] + 8.0f*edge_b[c]) * me_W[(HD + c)*HD + t];
    ws[WS_CVEC + t] = acc;
  }
}

// ================= precompute: bf16 MFMA fragment buffer =================
__global__ __launch_bounds__(64) void frag_kernel(
    const float* __restrict__ conv_W1, const float* __restrict__ conv_W2,
    const float* __restrict__ emlp_W, const float* __restrict__ motif_W,
    const float* __restrict__ atom_W, const float* __restrict__ edge_W,
    ushort_t* __restrict__ fbo)
{
  const int bid = blockIdx.x, l = threadIdx.x;
  int wi, kt, nt;
  if (bid < 256) { wi = bid >> 5; kt = (bid >> 3) & 3; nt = bid & 7; }
  else { int r = bid - 256; wi = 8 + (r >> 3); kt = 0; nt = r & 7; }
  const float* src; int Klim = 128;
  switch (wi) {
    case 0: src = conv_W1; break;
    case 1: src = conv_W2; break;
    case 2: src = conv_W1 + 16384; break;
    case 3: src = conv_W2 + 16384; break;
    case 4: src = emlp_W; break;
    case 5: src = emlp_W + 16384; break;
    case 6: src = emlp_W + 32768; break;
    case 7: src = motif_W; break;
    case 8: src = atom_W; Klim = 9; break;
    default: src = edge_W; Klim = 3; break;
  }
  size_t base = (wi < 8) ? (size_t)wi * 16384 : (size_t)131072 + (size_t)(wi - 8) * 4096;
  ushort_t* dst = fbo + base + ((size_t)(kt * 8 + nt) * 64 + l) * 8;
  #pragma unroll
  for (int j = 0; j < 8; ++j) {
    int k = kt * 32 + ((l >> 4) << 3) + j;
    int n = nt * 16 + (l & 15);
    float f = (k < Klim) ? src[k * HD + n] : 0.0f;
    dst[j] = f2bf(f);
  }
}

// ================= motif kernel =================
// FINAL FORM (r15): r12 structure + T14 async-STAGE split. Best measured:
// 516-522 us steady-state, WRITE_SIZE 25 MB (no spill), VGPR 104.
// Session conclusions baked in:
//  - launch_bounds(256,2): the 2nd arg only CAPS registers; caps below the
//    natural ~200 total regs spilled GBs of scratch (r3/4/10/13/16).
//  - occupancy is walled at 2 blocks/CU for this block shape (r19: LDS fit
//    below the 3-block line and occupancy still did not move).
//  - elementwise phases MUST be ds_read_b128-vectorized (r12: -25%).
//  - LDS-staged weights via double-buffered halves kill the in-flight
//    global-load register pressure that caused persistent spill (r9: -47%).
__global__ __launch_bounds__(256, 2) void motif_kernel(
    const float* __restrict__ x, const float* __restrict__ eag,
    const int* __restrict__ motif_nodes, const int* __restrict__ motif_types,
    const int* __restrict__ m_src, const int* __restrict__ m_dst,
    const int* __restrict__ m_eidx,
    const float* __restrict__ atom_b, const float* __restrict__ edge_b,
    const float* __restrict__ conv_b1, const float* __restrict__ conv_b2,
    const float* __restrict__ conv_eps,
    const float* __restrict__ attn_W, const float* __restrict__ attn_b,
    const float* __restrict__ emlp_b, const float* __restrict__ motif_b,
    const float* __restrict__ wsf, const ushort_t* __restrict__ fb,
    float* __restrict__ out)
{
  __shared__ __align__(16) char Hb[64 * 256];    // xp tails -> h0 -> z -> r -> h
  __shared__ __align__(16) char EAb[80 * 256];   // ep tails -> ea -> R -> cat(rows 0-15)
  __shared__ __align__(16) char Wbuf[2][16384];  // double-buffered 16KB weight halves
  __shared__ unsigned char zl[8][8][10];
  __shared__ unsigned char zcnt[8][8];
  __shared__ unsigned char gsr[80], gdr[80];
  __shared__ float qa[64];

  const int tid  = threadIdx.x;
  const int lane = tid & 63;
  const int wid  = tid >> 6;
  const int cl   = lane & 15;
  const int rg   = lane >> 4;
  const int rg16 = rg << 4;
  const int m0   = blockIdx.x * MPB;
  const int rb   = wid * 16;
  const int arow = rb + cl;
  const char* fbb = (const char*)fb;

  uint4 w0, w1, w2, w3;   // in-flight staging regs (T14 split)

#define LOADW(OFF) do { \
    const char* _s = fbb + (OFF); \
    w0 = *(const uint4*)(_s + (size_t)tid * 16); \
    w1 = *(const uint4*)(_s + 4096  + (size_t)tid * 16); \
    w2 = *(const uint4*)(_s + 8192  + (size_t)tid * 16); \
    w3 = *(const uint4*)(_s + 12288 + (size_t)tid * 16); \
  } while (0)
#define STOREW(B) do { \
    *(uint4*)(&Wbuf[B][(size_t)tid * 16]) = w0; \
    *(uint4*)(&Wbuf[B][4096  + (size_t)tid * 16]) = w1; \
    *(uint4*)(&Wbuf[B][8192  + (size_t)tid * 16]) = w2; \
    *(uint4*)(&Wbuf[B][12288 + (size_t)tid * 16]) = w3; \
  } while (0)
#define WT(B, T) (*(const short8*)(&Wbuf[B][(((T) * 64 + lane) * 16)]))

  // ---------- init: stage atom+edge (buf0) and W1(0)h0 (buf1); tails; tables ----------
  LOADW(FB_ATOM); STOREW(0);
  LOADW(FB_W1(0)); STOREW(1);
  if (tid < 64) qa[tid] = 0.0f;
  if (tid < 80) {
    int m = tid / 10;
    gsr[tid] = (unsigned char)(m * 8 + m_src[(size_t)m0 * 10 + tid]);
    gdr[tid] = (unsigned char)(m * 8 + m_dst[(size_t)m0 * 10 + tid]);
  }
  if (tid >= 192 && tid < 200) {
    int m = tid - 192;
    #pragma unroll
    for (int k = 0; k < 8; ++k) zcnt[m][k] = 0;
    for (int e = 0; e < 10; ++e) {
      int s = m_src[(size_t)(m0 + m) * 10 + e];
      int d = m_dst[(size_t)(m0 + m) * 10 + e];
      int c = zcnt[m][d];
      zl[m][d][c] = (unsigned char)(e | (s << 4));
      zcnt[m][d] = (unsigned char)(c + 1);
    }
  }
  for (int i = tid; i < 64 * 32; i += 256) {
    int row = i >> 5, k = i & 31;
    int nd = motif_nodes[(size_t)m0 * 8 + row];
    float f = (k < 9) ? x[(size_t)nd * 9 + k] : 0.0f;
    *(ushort_t*)(Hb + offS(row, 2 * k)) = f2bf(f);
  }
  for (int i = tid; i < 80 * 32; i += 256) {
    int row = i >> 5, k = i & 31;
    int ei = m_eidx[(size_t)m0 * 10 + row];
    float f = (k < 3) ? eag[(size_t)ei * 3 + k] : 0.0f;
    *(ushort_t*)(EAb + offS(row, 2 * k)) = f2bf(f);
  }
  __syncthreads();   // B1

  // ---------- embed: h0 = xp@atomW+b (tiles 0-7), ea = ep@edgeW+b (tiles 8-15) ----------
  {
    {
      short8 a = *(const short8*)(Hb + offS(arow, rg16));
      f32x4 acc[8];
      #pragma unroll
      for (int nt = 0; nt < 8; ++nt) { float bv = atom_b[nt * 16 + cl]; acc[nt] = f32x4{bv, bv, bv, bv}; }
      #pragma unroll
      for (int nt = 0; nt < 8; ++nt) acc[nt] = MFMA(a, WT(0, nt), acc[nt]);
      #pragma unroll
      for (int nt = 0; nt < 8; ++nt)
        #pragma unroll
        for (int i = 0; i < 4; ++i)
          *(ushort_t*)(Hb + off256(rb + rg * 4 + i, (nt * 16 + cl) * 2)) = f2bf(acc[nt][i]);
    }
    for (int mt = wid; mt < 5; mt += 4) {
      int rbe = mt * 16, row = rbe + cl;
      short8 a = *(const short8*)(EAb + offS(row, rg16));
      f32x4 acc[8];
      #pragma unroll
      for (int nt = 0; nt < 8; ++nt) { float bv = edge_b[nt * 16 + cl]; acc[nt] = f32x4{bv, bv, bv, bv}; }
      #pragma unroll
      for (int nt = 0; nt < 8; ++nt) acc[nt] = MFMA(a, WT(0, 8 + nt), acc[nt]);
      #pragma unroll
      for (int nt = 0; nt < 8; ++nt)
        #pragma unroll
        for (int i = 0; i < 4; ++i)
          *(ushort_t*)(EAb + off256(rbe + rg * 4 + i, (nt * 16 + cl) * 2)) = f2bf(acc[nt][i]);
    }
  }
  __syncthreads();   // B2

  // ---------- conv layers (in-place in Hb) ----------
  #pragma unroll 1
  for (int l = 0; l < 2; ++l) {
    const float epl = 1.0f + conv_eps[l];

    // z-phase: LOADW(W1 h1) up front; zf compute hides the load; STOREW at end
    LOADW(FB_W1(l) + 16384);
    float zf[4][8];
    #pragma unroll
    for (int it = 0; it < 4; ++it) {
      const int idx = tid + it * 256;
      const int row = idx >> 4;
      const int by  = (idx & 15) << 4;
      const int m = row >> 3, k = row & 7;
      short8 hv = *(const short8*)(Hb + off256(row, by));
      #pragma unroll
      for (int j = 0; j < 8; ++j) zf[it][j] = epl * bf2f((ushort_t)hv[j]);
      const int cnt = zcnt[m][k];
      for (int j2 = 0; j2 < cnt; ++j2) {
        const int pp = zl[m][k][j2];
        short8 ev = *(const short8*)(EAb + off256(m * 10 + (pp & 15), by));
        short8 sv = *(const short8*)(Hb  + off256(m * 8  + (pp >> 4), by));
        #pragma unroll
        for (int j = 0; j < 8; ++j)
          zf[it][j] += bf2f((ushort_t)ev[j]) * bf2f((ushort_t)sv[j]);
      }
    }
    STOREW(0);
    __syncthreads();   // all z reads done; buf0 (W1 h1) published
    #pragma unroll
    for (int it = 0; it < 4; ++it) {
      const int idx = tid + it * 256;
      store8(Hb + off256(idx >> 4, (idx & 15) << 4), zf[it]);
    }
    __syncthreads();   // z ready

    // GEMM1: r = relu(z @ W1 + b1), in-place Hb
    {
      LOADW(FB_W2(l));   // W2 h0 -> in flight across kt01+kt23
      f32x4 acc[8];
      #pragma unroll
      for (int nt = 0; nt < 8; ++nt) { float bv = conv_b1[l * HD + nt * 16 + cl]; acc[nt] = f32x4{bv, bv, bv, bv}; }
      #pragma unroll
      for (int kt = 0; kt < 2; ++kt) {
        short8 a = *(const short8*)(Hb + off256(arow, kt * 64 + rg16));
        #pragma unroll
        for (int nt = 0; nt < 8; ++nt) acc[nt] = MFMA(a, WT(1, kt * 8 + nt), acc[nt]);
      }
      __syncthreads();   // buf1 (W1 h0) reads done -> safe to overwrite below
      #pragma unroll
      for (int kt = 2; kt < 4; ++kt) {
        short8 a = *(const short8*)(Hb + off256(arow, kt * 64 + rg16));
        #pragma unroll
        for (int nt = 0; nt < 8; ++nt) acc[nt] = MFMA(a, WT(0, (kt - 2) * 8 + nt), acc[nt]);
      }
      STOREW(1);   // W2 h0 -> buf1
      #pragma unroll
      for (int nt = 0; nt < 8; ++nt)
        #pragma unroll
        for (int i = 0; i < 4; ++i)
          *(ushort_t*)(Hb + off256(rb + rg * 4 + i, (nt * 16 + cl) * 2)) = f2bf(fmaxf(acc[nt][i], 0.0f));
      __syncthreads();
    }
    // GEMM2: h = r @ W2 + b2, in-place Hb
    {
      LOADW(FB_W2(l) + 16384);   // W2 h1
      f32x4 acc[8];
      #pragma unroll
      for (int nt = 0; nt < 8; ++nt) { float bv = conv_b2[l * HD + nt * 16 + cl]; acc[nt] = f32x4{bv, bv, bv, bv}; }
      #pragma unroll
      for (int kt = 0; kt < 2; ++kt) {
        short8 a = *(const short8*)(Hb + off256(arow, kt * 64 + rg16));
        #pragma unroll
        for (int nt = 0; nt < 8; ++nt) acc[nt] = MFMA(a, WT(1, kt * 8 + nt), acc[nt]);
      }
      STOREW(0);   // W2 h1 -> buf0 (last read: GEMM1 kt23, barrier passed)
      __syncthreads();
      LOADW((l == 0) ? FB_W1(1) : FB_WA);   // next phase's h0
      #pragma unroll
      for (int kt = 2; kt < 4; ++kt) {
        short8 a = *(const short8*)(Hb + off256(arow, kt * 64 + rg16));
        #pragma unroll
        for (int nt = 0; nt < 8; ++nt) acc[nt] = MFMA(a, WT(0, (kt - 2) * 8 + nt), acc[nt]);
      }
      STOREW(1);   // -> buf1 (last read kt01, barrier passed)
      #pragma unroll
      for (int nt = 0; nt < 8; ++nt)
        #pragma unroll
        for (int i = 0; i < 4; ++i)
          *(ushort_t*)(Hb + off256(rb + rg * 4 + i, (nt * 16 + cl) * 2)) = f2bf(acc[nt][i]);
      __syncthreads();
    }
  }

  // ---------- attention (vectorized dots) ----------
  {
    int j = tid & 3;
    for (int r = tid >> 2; r < 80; r += 64) {
      float p = 0.0f;
      #pragma unroll
      for (int g = 0; g < 4; ++g) {
        short8 ev = *(const short8*)(EAb + off256(r, (j * 4 + g) << 4));
        const int c0 = j * 32 + g * 8;
        #pragma unroll
        for (int jj = 0; jj < 8; ++jj)
          p += bf2f((ushort_t)ev[jj]) * attn_W[HD + c0 + jj];
      }
      p += __shfl_xor(p, 1); p += __shfl_xor(p, 2);
      if (j == 0) {
        atomicAdd(&qa[gsr[r]], p);
        atomicAdd(&qa[gdr[r]], p);
      }
    }
  }
  __syncthreads();
  {
    int j = tid & 3, r = tid >> 2;
    float p = 0.0f;
    #pragma unroll
    for (int g = 0; g < 4; ++g) {
      short8 hv = *(const short8*)(Hb + off256(r, (j * 4 + g) << 4));
      const int c0 = j * 32 + g * 8;
      #pragma unroll
      for (int jj = 0; jj < 8; ++jj)
        p += bf2f((ushort_t)hv[jj]) * attn_W[c0 + jj];
    }
    p += __shfl_xor(p, 1); p += __shfl_xor(p, 2);
    if (j == 0) qa[r] = 1.0f / (1.0f + __expf(-(p + qa[r] + attn_b[0])));
  }
  __syncthreads();

  // ---------- fused emlp: R = h[src]@WA + h[dst]@WB + ea@WC -> EAb ----------
  {
    f32x4 accT[8], acc4[2];
    #pragma unroll
    for (int nt = 0; nt < 8; ++nt) accT[nt] = f32x4{0, 0, 0, 0};
    acc4[0] = f32x4{0, 0, 0, 0}; acc4[1] = f32x4{0, 0, 0, 0};
    const int r1 = 16 * wid + cl, r4 = 64 + cl;
    #pragma unroll 1
    for (int w = 0; w < 3; ++w) {
      const char* AB = (w == 2) ? EAb : Hb;
      const int a1 = (w == 0) ? (int)gsr[r1] : (w == 1) ? (int)gdr[r1] : r1;
      const int a4 = (w == 0) ? (int)gsr[r4] : (w == 1) ? (int)gdr[r4] : r4;
      LOADW(FB_WA + (size_t)w * 32768 + 16384);   // current weight h1
      #pragma unroll
      for (int kt = 0; kt < 2; ++kt) {
        short8 av  = *(const short8*)(AB + off256(a1, kt * 64 + rg16));
        short8 av4 = *(const short8*)(AB + off256(a4, kt * 64 + rg16));
        #pragma unroll
        for (int nt = 0; nt < 8; ++nt) accT[nt] = MFMA(av, WT(1, kt * 8 + nt), accT[nt]);
        acc4[0] = MFMA(av4, WT(1, kt * 8 + 2 * wid), acc4[0]);
        acc4[1] = MFMA(av4, WT(1, kt * 8 + 2 * wid + 1), acc4[1]);
      }
      STOREW(0);
      __syncthreads();
      LOADW(FB_WA + (size_t)(w + 1) * 32768);     // next weight h0 (w=2 -> WM h0)
      #pragma unroll
      for (int kt = 2; kt < 4; ++kt) {
        short8 av  = *(const short8*)(AB + off256(a1, kt * 64 + rg16));
        short8 av4 = *(const short8*)(AB + off256(a4, kt * 64 + rg16));
        #pragma unroll
        for (int nt = 0; nt < 8; ++nt) accT[nt] = MFMA(av, WT(0, (kt - 2) * 8 + nt), accT[nt]);
        acc4[0] = MFMA(av4, WT(0, (kt - 2) * 8 + 2 * wid), acc4[0]);
        acc4[1] = MFMA(av4, WT(0, (kt - 2) * 8 + 2 * wid + 1), acc4[1]);
      }
      STOREW(1);
      __syncthreads();
    }
    // epilogue: write R (all gather-reads completed at the last barrier)
    #pragma unroll
    for (int nt = 0; nt < 8; ++nt)
      #pragma unroll
      for (int i = 0; i < 4; ++i)
        *(ushort_t*)(EAb + off256(16 * wid + rg * 4 + i, (nt * 16 + cl) * 2)) = f2bf(accT[nt][i]);
    #pragma unroll
    for (int j = 0; j < 2; ++j)
      #pragma unroll
      for (int i = 0; i < 4; ++i)
        *(ushort_t*)(EAb + off256(64 + rg * 4 + i, ((2 * wid + j) * 16 + cl) * 2)) = f2bf(acc4[j][i]);
  }
  __syncthreads();

  // ---------- cat = hn + 0.1*sum relu(R+eb) (vectorized, tid<128) ----------
  LOADW(FB_WM + 16384);   // WM h1 in flight across cv compute
  float cv[8];
  if (tid < 128) {
    const int m  = tid >> 4;
    const int by = (tid & 15) << 4;
    const int c0 = (tid & 15) * 8;
    #pragma unroll
    for (int j = 0; j < 8; ++j) cv[j] = 0.0f;
    #pragma unroll
    for (int k = 0; k < 8; ++k) {
      short8 hv = *(const short8*)(Hb + off256(m * 8 + k, by));
      const float a = qa[m * 8 + k];
      #pragma unroll
      for (int j = 0; j < 8; ++j) cv[j] += a * bf2f((ushort_t)hv[j]);
    }
    float he[8];
    #pragma unroll
    for (int j = 0; j < 8; ++j) he[j] = 0.0f;
    #pragma unroll
    for (int e = 0; e < 10; ++e) {
      short8 rv = *(const short8*)(EAb + off256(m * 10 + e, by));
      #pragma unroll
      for (int j = 0; j < 8; ++j)
        he[j] += fmaxf(bf2f((ushort_t)rv[j]) + emlp_b[c0 + j], 0.0f);
    }
    #pragma unroll
    for (int j = 0; j < 8; ++j) cv[j] += 0.1f * he[j];
  }
  STOREW(0);
  __syncthreads();   // all R reads done before cat overwrites rows 0..15
  if (tid < 128) {
    store8(EAb + off256(tid >> 4, (tid & 15) << 4), cv);
  } else {
    const int i = tid - 128;
    short8 z{};
    *(short8*)(EAb + off256(8 + (i >> 4), (i & 15) << 4)) = z;
  }
  __syncthreads();

  // ---------- final: out = cat @ motifW_top + TM[type] + motif_b ----------
  {
    f32x4 acc[2];
    acc[0] = f32x4{0, 0, 0, 0}; acc[1] = f32x4{0, 0, 0, 0};
    #pragma unroll
    for (int kt = 0; kt < 2; ++kt) {
      short8 a = *(const short8*)(EAb + off256(cl, kt * 64 + rg16));
      #pragma unroll
      for (int j = 0; j < 2; ++j)
        acc[j] = MFMA(a, WT(1, kt * 8 + 2 * wid + j), acc[j]);
    }
    #pragma unroll
    for (int kt = 2; kt < 4; ++kt) {
      short8 a = *(const short8*)(EAb + off256(cl, kt * 64 + rg16));
      #pragma unroll
      for (int j = 0; j < 2; ++j)
        acc[j] = MFMA(a, WT(0, (kt - 2) * 8 + 2 * wid + j), acc[j]);
    }
    #pragma unroll
    for (int j = 0; j < 2; ++j)
      #pragma unroll
      for (int i = 0; i < 4; ++i) {
        int row = rg * 4 + i;
        if (row < 8) {
          int col = (wid * 2 + j) * 16 + cl;
          int ty = motif_types[m0 + row];
          out[(size_t)(m0 + row) * HD + col] = acc[j][i] + motif_b[col] + wsf[WS_TM + ty * HD + col];
        }
      }
  }
#undef LOADW
#undef STOREW
#undef WT
}

// ================= edge kernel =================
__global__ __launch_bounds__(256) void edge_kernel(
    const float* __restrict__ x, const float* __restrict__ eag,
    const int* __restrict__ motif_types, const int* __restrict__ mei,
    const int* __restrict__ attr_nodes, const int* __restrict__ attr_edges,
    const float* __restrict__ ws, float* __restrict__ out, int ME_)
{
  __shared__ int   ani[EPB][6];
  __shared__ int   aei[EPB][8];
  __shared__ float sxl[EPB][9];
  __shared__ float sel[EPB][3];
  __shared__ int   tei[EPB];

  const int tid = threadIdx.x;
  const int t = tid & (HD - 1);
  const int g = tid >> 7;
  const int me0 = blockIdx.x * EPB;

  if (tid < EPB*6) ani[tid/6][tid%6] = attr_nodes[(size_t)(me0 + tid/6)*6 + tid%6];
  if (tid >= 32 && tid < 32 + EPB*8) { int i = tid-32; aei[i/8][i%8] = attr_edges[(size_t)(me0 + i/8)*8 + i%8]; }
  if (tid >= 64 && tid < 64 + EPB) {
    const int e = tid - 64;
    const int a0 = mei[me0 + e], b0 = mei[ME_ + me0 + e];
    tei[e] = motif_types[a0]*4 + motif_types[b0];
  }
  __syncthreads();

  if (tid < EPB*9) {
    const int e = tid/9, a = tid%9;
    float s = 0.0f;
    #pragma unroll
    for (int p = 0; p < 6; ++p) s += x[(size_t)ani[e][p]*9 + a];
    sxl[e][a] = s;
  }
  if (tid >= 32 && tid < 32 + EPB*3) {
    const int i = tid-32, e = i/3, a = i%3;
    float s = 0.0f;
    #pragma unroll
    for (int p = 0; p < 8; ++p) s += eag[(size_t)aei[e][p]*3 + a];
    sel[e][a] = s;
  }
  __syncthreads();

  float acc = ws[WS_CVEC + t] + ws[WS_TE + tei[g]*HD + t];
  #pragma unroll
  for (int a = 0; a < 9; ++a) acc += sxl[g][a] * ws[WS_AW2 + a*HD + t];
  #pragma unroll
  for (int a = 0; a < 3; ++a) acc += sel[g][a] * ws[WS_EW2 + a*HD + t];
  out[(size_t)(me0 + g)*HD + t] = acc;
}

extern "C" void kernel_launch(void* const* d_in, const int* in_sizes, int n_in,
                              void* d_out, int out_size, void* d_ws, size_t ws_size,
                              hipStream_t stream) {
  const float* x          = (const float*)d_in[0];
  const float* eag        = (const float*)d_in[1];
  const int*   motif_nodes= (const int*)d_in[2];
  const int*   motif_types= (const int*)d_in[3];
  const int*   m_src      = (const int*)d_in[4];
  const int*   m_dst      = (const int*)d_in[5];
  const int*   m_eidx     = (const int*)d_in[6];
  const int*   mei        = (const int*)d_in[7];
  const int*   attr_nodes = (const int*)d_in[8];
  const int*   attr_edges = (const int*)d_in[9];
  const float* type_emb   = (const float*)d_in[10];
  const float* atom_W     = (const float*)d_in[11];
  const float* atom_b     = (const float*)d_in[12];
  const float* edge_W     = (const float*)d_in[13];
  const float* edge_b     = (const float*)d_in[14];
  const float* conv_W1    = (const float*)d_in[15];
  const float* conv_b1    = (const float*)d_in[16];
  const float* conv_W2    = (const float*)d_in[17];
  const float* conv_b2    = (const float*)d_in[18];
  const float* conv_eps   = (const float*)d_in[19];
  const float* attn_W     = (const float*)d_in[20];
  const float* attn_b     = (const float*)d_in[21];
  const float* emlp_W     = (const float*)d_in[22];
  const float* emlp_b     = (const float*)d_in[23];
  const float* motif_W    = (const float*)d_in[24];
  const float* motif_b    = (const float*)d_in[25];
  const float* me_W       = (const float*)d_in[26];
  const float* me_b       = (const float*)d_in[27];

  const int N_  = in_sizes[0] / 9;
  const int M_  = in_sizes[2] / 8;
  const int ME_ = in_sizes[7] / 2;

  float* wsf = (float*)d_ws;
  ushort_t* fb = (ushort_t*)((char*)d_ws + FB_OFF);
  float* out = (float*)d_out;

  precompute_kernel<<<33, 128, 0, stream>>>(type_emb, atom_W, atom_b, edge_W, edge_b,
                                            motif_W, me_W, me_b, (float)N_, wsf);
  frag_kernel<<<272, 64, 0, stream>>>(conv_W1, conv_W2, emlp_W, motif_W, atom_W, edge_W, fb);
  motif_kernel<<<M_/MPB, 256, 0, stream>>>(x, eag, motif_nodes, motif_types, m_src, m_dst, m_eidx,
      atom_b, edge_b, conv_b1, conv_b2, conv_eps, attn_W, attn_b, emlp_b, motif_b,
      wsf, fb, out);
  edge_kernel<<<ME_/EPB, 256, 0, stream>>>(x, eag, motif_types, mei, attr_nodes, attr_edges,
                                           wsf, out + (size_t)M_*HD, ME_);
}